// Round 1
// baseline (372.264 us; speedup 1.0000x reference)
//
#include <hip/hip_runtime.h>

#define D_DIM 1024
#define H_DIM 1024
#define E_NUM 8
#define BM 256
#define BN 256        // in interleaved v/g column space (2*H per expert)
#define BK 64
#define NT (D_DIM / BK)
#define CAP 5120      // per-expert bucket capacity (mean 4096, sigma ~60; >17 sigma)
#define RT_TOK 32     // tokens per router block

typedef __attribute__((ext_vector_type(8))) _Float16 h8v;
typedef __attribute__((ext_vector_type(4))) float f4v;

__device__ __forceinline__ unsigned short f2h(float f) {
  union { _Float16 h; unsigned short u; } c;
  c.h = (_Float16)f;  // v_cvt_f16_f32, RNE
  return c.u;
}

// async 16B global->LDS DMA; LDS dest = wave-uniform base + lane*16
__device__ __forceinline__ void gl2lds16(const void* g, void* l) {
  __builtin_amdgcn_global_load_lds(
      (const __attribute__((address_space(1))) unsigned int*)g,
      (__attribute__((address_space(3))) unsigned int*)l, 16, 0, 0);
}

// ---------------- phase 0: W [E][D][H] fp32 -> Wc [E][2H][D] fp16 interleaved ----
// n-row mapping: n = (h>>4)*32 + mat*16 + (h&15)  (mat 0=Wv, 1=Wg)
// => adjacent 16-col groups in n-space are (v,g) pairs over the same 16 h-cols.
__global__ __launch_bounds__(256) void transpose_w_kernel(
    const float* __restrict__ Wv, const float* __restrict__ Wg,
    unsigned short* __restrict__ Wc) {
  __shared__ float tile[64][65];  // pad 65: 2-way max on both phases
  int z = blockIdx.z;             // 0..15: bit0 = which matrix, rest = expert
  const float* W = (z & 1) ? Wg : Wv;
  int mat = z & 1;
  int e = z >> 1;
  int h0 = blockIdx.x * 64, d0 = blockIdx.y * 64;
  const float* Wp = W + (size_t)e * D_DIM * H_DIM;
  unsigned short* Wcp = Wc + (size_t)e * (2 * H_DIM) * D_DIM;
  int t = threadIdx.x;
#pragma unroll
  for (int j = 0; j < 4; j++) {  // 1024 float4 loads, 4/thread
    int id = t + 256 * j;
    int dd = id >> 4, hc = id & 15;
    float4 v = *(const float4*)(Wp + (size_t)(d0 + dd) * H_DIM + h0 + hc * 4);
    tile[dd][hc * 4 + 0] = v.x;
    tile[dd][hc * 4 + 1] = v.y;
    tile[dd][hc * 4 + 2] = v.z;
    tile[dd][hc * 4 + 3] = v.w;
  }
  __syncthreads();
#pragma unroll
  for (int j = 0; j < 2; j++) {  // 512 uint4 (8-half) stores, 2/thread
    int id = t + 256 * j;
    int h_ = id >> 3, dc = id & 7;
    unsigned short tmp[8];
#pragma unroll
    for (int k = 0; k < 8; k++) tmp[k] = f2h(tile[dc * 8 + k][h_]);
    int hg = h0 + h_;
    int ng = ((hg >> 4) << 5) | (mat << 4) | (hg & 15);
    *(uint4*)(Wcp + (size_t)ng * D_DIM + d0 + dc * 8) = *(uint4*)tmp;
  }
}

// ---------------- phase 1: router (fp32 exact top-2) + fused x->fp16 convert ----
// counts[] padded: expert e at counts[e*32] (128 B apart -> no line contention).
__global__ __launch_bounds__(256) void router_kernel(
    const float4* __restrict__ x4, const float4* __restrict__ gw4,
    const float* __restrict__ gb, int* __restrict__ counts,
    int* __restrict__ bucket, float* __restrict__ scoreB,
    int* __restrict__ slotOf, ushort4* __restrict__ xh4, int B) {
  __shared__ float4 gwS[E_NUM * 256];  // 32 KB: all 8 expert rows
  __shared__ short eSelS[RT_TOK][2];
  __shared__ float sSelS[RT_TOK][2];
  __shared__ int lCnt[E_NUM], lBase[E_NUM];
  __shared__ unsigned char lOff[RT_TOK][2];
  int tid = threadIdx.x;
  for (int i = tid; i < E_NUM * 256; i += 256) gwS[i] = gw4[i];
  if (tid < E_NUM) lCnt[tid] = 0;
  __syncthreads();
  int wid = tid >> 6, lane = tid & 63;
  for (int rep = 0; rep < RT_TOK / 4; rep++) {
    int t = wid * (RT_TOK / 4) + rep;
    int b = blockIdx.x * RT_TOK + t;
    float acc[E_NUM];
#pragma unroll
    for (int e = 0; e < E_NUM; e++) acc[e] = 0.0f;
#pragma unroll
    for (int i = 0; i < 4; i++) {
      float4 xv = x4[(size_t)b * 256 + i * 64 + lane];
      ushort4 o;
      o.x = f2h(xv.x); o.y = f2h(xv.y); o.z = f2h(xv.z); o.w = f2h(xv.w);
      xh4[(size_t)b * 256 + i * 64 + lane] = o;  // fused fp16 convert
#pragma unroll
      for (int e = 0; e < E_NUM; e++) {
        float4 w = gwS[e * 256 + i * 64 + lane];
        acc[e] += xv.x * w.x + xv.y * w.y + xv.z * w.z + xv.w * w.w;
      }
    }
#pragma unroll
    for (int e = 0; e < E_NUM; e++) {
#pragma unroll
      for (int off = 32; off > 0; off >>= 1) acc[e] += __shfl_down(acc[e], off);
    }
    if (lane == 0) {
      float l[E_NUM];
#pragma unroll
      for (int e = 0; e < E_NUM; e++) l[e] = acc[e] + gb[e];
      int i0 = 0;
#pragma unroll
      for (int e = 1; e < E_NUM; e++) if (l[e] > l[i0]) i0 = e;
      int i1 = (i0 == 0) ? 1 : 0;
#pragma unroll
      for (int e = 0; e < E_NUM; e++) if (e != i0 && l[e] > l[i1]) i1 = e;
      float mx = l[i0];
      float denom = 0.0f;
#pragma unroll
      for (int e = 0; e < E_NUM; e++) denom += __expf(l[e] - mx);
      eSelS[t][0] = (short)i0; sSelS[t][0] = 1.0f / denom;
      eSelS[t][1] = (short)i1; sSelS[t][1] = __expf(l[i1] - mx) / denom;
    }
  }
  __syncthreads();
  if (tid < RT_TOK) {
    lOff[tid][0] = (unsigned char)atomicAdd(&lCnt[eSelS[tid][0]], 1);
    lOff[tid][1] = (unsigned char)atomicAdd(&lCnt[eSelS[tid][1]], 1);
  }
  __syncthreads();
  if (tid < E_NUM) lBase[tid] = atomicAdd(&counts[tid * 32], lCnt[tid]);
  __syncthreads();
  if (tid < RT_TOK) {
    int b = blockIdx.x * RT_TOK + tid;
#pragma unroll
    for (int j = 0; j < 2; j++) {
      int e = eSelS[tid][j];
      int pos = lBase[e] + lOff[tid][j];
      if (pos < CAP) {
        int slot = e * CAP + pos;
        bucket[slot] = b;
        scoreB[slot] = sSelS[tid][j];
        slotOf[b * 2 + j] = slot;
      }
    }
  }
}

// ---------------- phase 2: grouped GEMM (interleaved v/g) + SwiGLU ----------------
// 256x256x64 tile, 8 waves (2M x 4N), 130 KB LDS double-buffer, phase-split
// K-loop with counted vmcnt (T3+T4) + setprio around MFMA clusters (T5).
//
// Wave sub-tiles are half-split so each phase depends on exactly ONE staged
// half-tile: wave wm owns A rows {wm*64..+63} u {128+wm*64..+63}; wave wn owns
// B rows {wn*32..+31} u {128+wn*32..+31}.  Phases per K-tile kt (buf c=kt&1):
//   P0: read Af(m-lo)+Bf(n-lo); stage A-lo(kt+1); MFMA q(0,0); vmcnt(4)
//   P1: read Af(m-hi);          stage B-lo(kt+1); MFMA q(4,0); vmcnt(4)
//   P2: read Bf(n-hi);          stage A-hi(kt+1); MFMA q(4,2); (no wait)
//   P3: re-read Af(m-lo);       stage B-hi(kt+1); MFMA q(0,2); vmcnt(4)
// FIFO invariant at iter top: 4 outstanding DMAs (A-hi,B-hi of tile kt);
// vmcnt(4) at each marked point retires exactly the half-tile the NEXT phase
// reads, while 2-4 half-tiles stay in flight across every barrier (never 0).
//
// LDS layout: [row][k], 16B chunk c at position (c ^ (row&7)); staging applies
// the inverse swizzle to the per-lane GLOBAL source address (lds dest linear).
#define READ_AF(RBASE)                                                         \
  {                                                                            \
    _Pragma("unroll") for (int m = 0; m < 4; m++) {                            \
      _Pragma("unroll") for (int s = 0; s < 2; s++) {                          \
        int row = (RBASE) + m * 16 + lr;                                       \
        int c = s * 4 + quad;                                                  \
        af[m][s] = *(const h8v*)(Ac + row * BK + ((c ^ (row & 7)) << 3));      \
      }                                                                        \
    }                                                                          \
  }
#define READ_BF(RBASE)                                                         \
  {                                                                            \
    _Pragma("unroll") for (int n = 0; n < 2; n++) {                            \
      _Pragma("unroll") for (int s = 0; s < 2; s++) {                          \
        int row = (RBASE) + n * 16 + lr;                                       \
        int c = s * 4 + quad;                                                  \
        bf[n][s] = *(const h8v*)(Bc + row * BK + ((c ^ (row & 7)) << 3));      \
      }                                                                        \
    }                                                                          \
  }
#define MFMA_Q(MO, NO)                                                         \
  {                                                                            \
    _Pragma("unroll") for (int m = 0; m < 4; m++) {                            \
      _Pragma("unroll") for (int n = 0; n < 2; n++) {                          \
        _Pragma("unroll") for (int s = 0; s < 2; s++) {                        \
          acc[(MO) + m][(NO) + n] = __builtin_amdgcn_mfma_f32_16x16x32_f16(    \
              af[m][s], bf[n][s], acc[(MO) + m][(NO) + n], 0, 0, 0);           \
        }                                                                      \
      }                                                                        \
    }                                                                          \
  }

template <bool USE_PARTIAL>
__global__ __launch_bounds__(512, 2) void moe_gemm_kernel(
    const unsigned short* __restrict__ xh, const unsigned short* __restrict__ Wc,
    const int* __restrict__ counts, const int* __restrict__ bucket,
    const float* __restrict__ scoreB, _Float16* __restrict__ partial,
    float* __restrict__ out, int B) {
  int e = blockIdx.z;
  int cnt = counts[e * 32];
  int m0 = blockIdx.x * BM;
  if (m0 >= cnt) return;
  int n0 = blockIdx.y * BN;

  __shared__ unsigned short As[2][BM * BK];  // 64 KB
  __shared__ unsigned short Bs[2][BN * BK];  // 64 KB
  __shared__ int tokS[BM];
  __shared__ float scS[BM];

  int tid = threadIdx.x;
  if (tid < BM) {
    int gr = m0 + tid;
    bool vld = gr < cnt;
    tokS[tid] = vld ? bucket[e * CAP + gr] : 0;
    scS[tid] = vld ? scoreB[e * CAP + gr] : 0.0f;  // padded rows contribute 0
  }
  __syncthreads();

  int wid = tid >> 6, lane = tid & 63;
  int wm = wid & 1, wn = wid >> 1;  // 2 (M) x 4 (N)
  int quad = lane >> 4, lr = lane & 15;

  // staging source pointers: thread covers row i*64 + (tid>>3), chunk tid&7,
  // with inverse XOR swizzle folded into the global k-offset.
  int rA = tid >> 3;                      // 0..63
  int ksw = ((tid & 7) ^ (rA & 7)) * 8;   // halves
  const unsigned short* WcE = Wc + (size_t)e * (2 * H_DIM) * D_DIM;
  const unsigned short* pA[4];
  const unsigned short* pB[4];
#pragma unroll
  for (int i = 0; i < 4; i++) {
    pA[i] = xh + (size_t)tokS[i * 64 + rA] * D_DIM + ksw;
    pB[i] = WcE + (size_t)(n0 + i * 64 + rA) * D_DIM + ksw;
  }
  int dst0 = tid * 8;  // halves; half-tile i at +i*4096

  f4v acc[8][4];
#pragma unroll
  for (int m = 0; m < 8; m++)
#pragma unroll
    for (int n = 0; n < 4; n++) acc[m][n] = (f4v){0.f, 0.f, 0.f, 0.f};

  // prologue: stage tile 0 (issue order defines FIFO: A-lo, B-lo, A-hi, B-hi)
  gl2lds16(pA[0], &As[0][0 * 4096 + dst0]);
  gl2lds16(pA[1], &As[0][1 * 4096 + dst0]);
  gl2lds16(pB[0], &Bs[0][0 * 4096 + dst0]);
  gl2lds16(pB[1], &Bs[0][1 * 4096 + dst0]);
  gl2lds16(pA[2], &As[0][2 * 4096 + dst0]);
  gl2lds16(pA[3], &As[0][3 * 4096 + dst0]);
  gl2lds16(pB[2], &Bs[0][2 * 4096 + dst0]);
  gl2lds16(pB[3], &Bs[0][3 * 4096 + dst0]);
#pragma unroll
  for (int i = 0; i < 4; i++) { pA[i] += BK; pB[i] += BK; }
  asm volatile("s_waitcnt vmcnt(4)" ::: "memory");  // A-lo,B-lo(0) landed
  __builtin_amdgcn_s_barrier();

  h8v af[4][2], bf[2][2];
  int cb = 0;
  for (int kt = 0; kt < NT; ++kt) {
    int nb = cb ^ 1;
    const unsigned short* Ac = As[cb];
    const unsigned short* Bc = Bs[cb];
    unsigned short* An = As[nb];
    unsigned short* Bn = Bs[nb];

    // ---- P0: MFMA (m-lo, n-lo); stage A-lo(kt+1) ----
    READ_AF(wm * 64);
    READ_BF(wn * 32);
    gl2lds16(pA[0], An + 0 * 4096 + dst0);
    gl2lds16(pA[1], An + 1 * 4096 + dst0);
    __builtin_amdgcn_s_barrier();
    __builtin_amdgcn_s_setprio(1);
    MFMA_Q(0, 0);
    __builtin_amdgcn_s_setprio(0);
    asm volatile("s_waitcnt vmcnt(4)" ::: "memory");  // A-hi(kt) landed
    __builtin_amdgcn_s_barrier();

    // ---- P1: MFMA (m-hi, n-lo); stage B-lo(kt+1) ----
    READ_AF(128 + wm * 64);
    gl2lds16(pB[0], Bn + 0 * 4096 + dst0);
    gl2lds16(pB[1], Bn + 1 * 4096 + dst0);
    __builtin_amdgcn_s_barrier();
    __builtin_amdgcn_s_setprio(1);
    MFMA_Q(4, 0);
    __builtin_amdgcn_s_setprio(0);
    asm volatile("s_waitcnt vmcnt(4)" ::: "memory");  // B-hi(kt) landed
    __builtin_amdgcn_s_barrier();

    // ---- P2: MFMA (m-hi, n-hi); stage A-hi(kt+1) ----
    READ_BF(128 + wn * 32);
    gl2lds16(pA[2], An + 2 * 4096 + dst0);
    gl2lds16(pA[3], An + 3 * 4096 + dst0);
    __builtin_amdgcn_s_barrier();
    __builtin_amdgcn_s_setprio(1);
    MFMA_Q(4, 2);
    __builtin_amdgcn_s_setprio(0);
    __builtin_amdgcn_s_barrier();  // P3 re-reads resident A-lo: no wait needed

    // ---- P3: MFMA (m-lo, n-hi); stage B-hi(kt+1) ----
    READ_AF(wm * 64);
    gl2lds16(pB[2], Bn + 2 * 4096 + dst0);
    gl2lds16(pB[3], Bn + 3 * 4096 + dst0);
    __builtin_amdgcn_s_barrier();
    __builtin_amdgcn_s_setprio(1);
    MFMA_Q(0, 2);
    __builtin_amdgcn_s_setprio(0);
    asm volatile("s_waitcnt vmcnt(4)" ::: "memory");  // A-lo,B-lo(kt+1) landed
    __builtin_amdgcn_s_barrier();

    cb = nb;
    if (kt < NT - 2) {  // clamp: last iter re-stages tile NT-1 (L2-hot, keeps counts uniform)
#pragma unroll
      for (int i = 0; i < 4; i++) { pA[i] += BK; pB[i] += BK; }
    }
  }
  asm volatile("s_waitcnt vmcnt(0)" ::: "memory");  // drain DMAs before LDS dealloc

  // epilogue: acc[m][2p]=v, acc[m][2p+1]=g at identical h (interleaved Wc).
  // C/D layout: col = lane&15, row = quad*4 + reg  [measured m89/m91]
  int hb = blockIdx.y * 128 + wn * 16 + lr;
#pragma unroll
  for (int m = 0; m < 8; m++) {
    int rb = ((m < 4) ? (wm * 64 + m * 16) : (128 + wm * 64 + (m - 4) * 16)) + quad * 4;
#pragma unroll
    for (int r = 0; r < 4; r++) {
      int rr = rb + r;
      float sc = scS[rr];
      if (USE_PARTIAL) {
        _Float16* pr = partial + (size_t)(e * CAP + m0 + rr) * H_DIM;
#pragma unroll
        for (int p = 0; p < 2; p++) {
          float v = acc[m][2 * p][r];
          float g = acc[m][2 * p + 1][r];
          pr[hb + p * 64] = (_Float16)(v * sc / (1.0f + __expf(-g)));
        }
      } else {
        int tok = tokS[rr];
#pragma unroll
        for (int p = 0; p < 2; p++) {
          float v = acc[m][2 * p][r];
          float g = acc[m][2 * p + 1][r];
          atomicAdd(&out[(size_t)tok * H_DIM + hb + p * 64],
                    v * sc / (1.0f + __expf(-g)));
        }
      }
    }
  }
}

// ---------------- phase 3: gather (out[b] = partial[s0] + partial[s1]) ----------
__global__ __launch_bounds__(256) void gather_kernel(
    const _Float16* __restrict__ partial, const int* __restrict__ slotOf,
    float* __restrict__ out) {
  int b = blockIdx.x * 2 + (threadIdx.x >> 7);  // 2 tokens/block
  int t = threadIdx.x & 127;                     // 8 halves per thread
  int s0 = slotOf[b * 2], s1 = slotOf[b * 2 + 1];
  if ((unsigned)s0 >= E_NUM * CAP) s0 = 0;  // poison guard (overflow ~impossible)
  if ((unsigned)s1 >= E_NUM * CAP) s1 = 0;
  h8v a = ((const h8v*)(partial + (size_t)s0 * H_DIM))[t];
  h8v c = ((const h8v*)(partial + (size_t)s1 * H_DIM))[t];
  float4 o0, o1;
  o0.x = (float)a[0] + (float)c[0];
  o0.y = (float)a[1] + (float)c[1];
  o0.z = (float)a[2] + (float)c[2];
  o0.w = (float)a[3] + (float)c[3];
  o1.x = (float)a[4] + (float)c[4];
  o1.y = (float)a[5] + (float)c[5];
  o1.z = (float)a[6] + (float)c[6];
  o1.w = (float)a[7] + (float)c[7];
  float4* op = (float4*)(out + (size_t)b * H_DIM);
  op[t * 2] = o0;
  op[t * 2 + 1] = o1;
}

extern "C" void kernel_launch(void* const* d_in, const int* in_sizes, int n_in,
                              void* d_out, int out_size, void* d_ws, size_t ws_size,
                              hipStream_t stream) {
  const float* x = (const float*)d_in[0];
  const float* Wv = (const float*)d_in[1];
  const float* Wg = (const float*)d_in[2];
  const float* gw = (const float*)d_in[3];
  const float* gb = (const float*)d_in[4];
  float* out = (float*)d_out;
  const int B = in_sizes[0] / D_DIM;  // 16384

  char* ws = (char*)d_ws;
  unsigned short* xh = (unsigned short*)ws;                       // 32 MB
  size_t off = (size_t)B * D_DIM * 2;
  unsigned short* Wc = (unsigned short*)(ws + off);               // 32 MB (interleaved v/g)
  off += (size_t)E_NUM * (2 * H_DIM) * D_DIM * 2;
  int* counts = (int*)(ws + off);                                 // 8 padded counters
  off += 4096;
  int* bucket = (int*)(ws + off);                                 // E*CAP ints
  off += (size_t)E_NUM * CAP * 4;
  float* scoreB = (float*)(ws + off);                             // E*CAP floats
  off += (size_t)E_NUM * CAP * 4;
  int* slotOf = (int*)(ws + off);                                 // B*2 ints
  off += (size_t)B * 2 * 4;
  _Float16* partial = (_Float16*)(ws + off);                      // E*CAP*H fp16 = 80 MB
  size_t need = off + (size_t)E_NUM * CAP * H_DIM * 2;
  bool use_partial = ws_size >= need;

  hipMemsetAsync(counts, 0, 4096, stream);
  if (!use_partial) hipMemsetAsync(d_out, 0, (size_t)out_size * 4, stream);

  router_kernel<<<B / RT_TOK, 256, 0, stream>>>(
      (const float4*)x, (const float4*)gw, gb, counts, bucket, scoreB, slotOf,
      (ushort4*)xh, B);
  transpose_w_kernel<<<dim3(H_DIM / 64, D_DIM / 64, 2 * E_NUM), 256, 0, stream>>>(
      Wv, Wg, Wc);
  if (use_partial) {
    moe_gemm_kernel<true><<<dim3(CAP / BM, (2 * H_DIM) / BN, E_NUM), 512, 0, stream>>>(
        xh, Wc, counts, bucket, scoreB, partial, out, B);
    gather_kernel<<<B / 2, 256, 0, stream>>>(partial, slotOf, out);
  } else {
    moe_gemm_kernel<false><<<dim3(CAP / BM, (2 * H_DIM) / BN, E_NUM), 512, 0, stream>>>(
        xh, Wc, counts, bucket, scoreB, partial, out, B);
  }
}

// Round 2
// 371.416 us; speedup vs baseline: 1.0023x; 1.0023x over previous
//
#include <hip/hip_runtime.h>

#define D_DIM 1024
#define H_DIM 1024
#define E_NUM 8
#define BM 256
#define BN 256        // in interleaved v/g column space (2*H per expert)
#define BK 64
#define NT (D_DIM / BK)
#define CAP 5120      // per-expert bucket capacity (mean 4096, sigma ~60; >17 sigma)
#define RT_TOK 32     // tokens per router block

typedef __attribute__((ext_vector_type(8))) _Float16 h8v;
typedef __attribute__((ext_vector_type(4))) float f4v;

__device__ __forceinline__ unsigned short f2h(float f) {
  union { _Float16 h; unsigned short u; } c;
  c.h = (_Float16)f;  // v_cvt_f16_f32, RNE
  return c.u;
}

// async 16B global->LDS DMA; LDS dest = wave-uniform base + lane*16
__device__ __forceinline__ void gl2lds16(const void* g, void* l) {
  __builtin_amdgcn_global_load_lds(
      (const __attribute__((address_space(1))) unsigned int*)g,
      (__attribute__((address_space(3))) unsigned int*)l, 16, 0, 0);
}

// generic (flat) LDS pointer -> 32-bit LDS byte offset for raw ds_read asm
__device__ __forceinline__ unsigned ldsaddr(const void* p) {
  return (unsigned)(unsigned long long)(const __attribute__((address_space(3))) void*)p;
}

// ---------------- phase 0: W [E][D][H] fp32 -> Wc [E][2H][D] fp16 interleaved ----
// n-row mapping: n = (h>>4)*32 + mat*16 + (h&15)  (mat 0=Wv, 1=Wg)
// => adjacent 16-col groups in n-space are (v,g) pairs over the same 16 h-cols.
__global__ __launch_bounds__(256) void transpose_w_kernel(
    const float* __restrict__ Wv, const float* __restrict__ Wg,
    unsigned short* __restrict__ Wc) {
  __shared__ float tile[64][65];  // pad 65: 2-way max on both phases
  int z = blockIdx.z;             // 0..15: bit0 = which matrix, rest = expert
  const float* W = (z & 1) ? Wg : Wv;
  int mat = z & 1;
  int e = z >> 1;
  int h0 = blockIdx.x * 64, d0 = blockIdx.y * 64;
  const float* Wp = W + (size_t)e * D_DIM * H_DIM;
  unsigned short* Wcp = Wc + (size_t)e * (2 * H_DIM) * D_DIM;
  int t = threadIdx.x;
#pragma unroll
  for (int j = 0; j < 4; j++) {  // 1024 float4 loads, 4/thread
    int id = t + 256 * j;
    int dd = id >> 4, hc = id & 15;
    float4 v = *(const float4*)(Wp + (size_t)(d0 + dd) * H_DIM + h0 + hc * 4);
    tile[dd][hc * 4 + 0] = v.x;
    tile[dd][hc * 4 + 1] = v.y;
    tile[dd][hc * 4 + 2] = v.z;
    tile[dd][hc * 4 + 3] = v.w;
  }
  __syncthreads();
#pragma unroll
  for (int j = 0; j < 2; j++) {  // 512 uint4 (8-half) stores, 2/thread
    int id = t + 256 * j;
    int h_ = id >> 3, dc = id & 7;
    unsigned short tmp[8];
#pragma unroll
    for (int k = 0; k < 8; k++) tmp[k] = f2h(tile[dc * 8 + k][h_]);
    int hg = h0 + h_;
    int ng = ((hg >> 4) << 5) | (mat << 4) | (hg & 15);
    *(uint4*)(Wcp + (size_t)ng * D_DIM + d0 + dc * 8) = *(uint4*)tmp;
  }
}

// ---------------- phase 1: router (fp32 exact top-2) + fused x->fp16 convert ----
// counts[] padded: expert e at counts[e*32] (128 B apart -> no line contention).
__global__ __launch_bounds__(256) void router_kernel(
    const float4* __restrict__ x4, const float4* __restrict__ gw4,
    const float* __restrict__ gb, int* __restrict__ counts,
    int* __restrict__ bucket, float* __restrict__ scoreB,
    int* __restrict__ slotOf, ushort4* __restrict__ xh4, int B) {
  __shared__ float4 gwS[E_NUM * 256];  // 32 KB: all 8 expert rows
  __shared__ short eSelS[RT_TOK][2];
  __shared__ float sSelS[RT_TOK][2];
  __shared__ int lCnt[E_NUM], lBase[E_NUM];
  __shared__ unsigned char lOff[RT_TOK][2];
  int tid = threadIdx.x;
  for (int i = tid; i < E_NUM * 256; i += 256) gwS[i] = gw4[i];
  if (tid < E_NUM) lCnt[tid] = 0;
  __syncthreads();
  int wid = tid >> 6, lane = tid & 63;
  for (int rep = 0; rep < RT_TOK / 4; rep++) {
    int t = wid * (RT_TOK / 4) + rep;
    int b = blockIdx.x * RT_TOK + t;
    float acc[E_NUM];
#pragma unroll
    for (int e = 0; e < E_NUM; e++) acc[e] = 0.0f;
#pragma unroll
    for (int i = 0; i < 4; i++) {
      float4 xv = x4[(size_t)b * 256 + i * 64 + lane];
      ushort4 o;
      o.x = f2h(xv.x); o.y = f2h(xv.y); o.z = f2h(xv.z); o.w = f2h(xv.w);
      xh4[(size_t)b * 256 + i * 64 + lane] = o;  // fused fp16 convert
#pragma unroll
      for (int e = 0; e < E_NUM; e++) {
        float4 w = gwS[e * 256 + i * 64 + lane];
        acc[e] += xv.x * w.x + xv.y * w.y + xv.z * w.z + xv.w * w.w;
      }
    }
#pragma unroll
    for (int e = 0; e < E_NUM; e++) {
#pragma unroll
      for (int off = 32; off > 0; off >>= 1) acc[e] += __shfl_down(acc[e], off);
    }
    if (lane == 0) {
      float l[E_NUM];
#pragma unroll
      for (int e = 0; e < E_NUM; e++) l[e] = acc[e] + gb[e];
      int i0 = 0;
#pragma unroll
      for (int e = 1; e < E_NUM; e++) if (l[e] > l[i0]) i0 = e;
      int i1 = (i0 == 0) ? 1 : 0;
#pragma unroll
      for (int e = 0; e < E_NUM; e++) if (e != i0 && l[e] > l[i1]) i1 = e;
      float mx = l[i0];
      float denom = 0.0f;
#pragma unroll
      for (int e = 0; e < E_NUM; e++) denom += __expf(l[e] - mx);
      eSelS[t][0] = (short)i0; sSelS[t][0] = 1.0f / denom;
      eSelS[t][1] = (short)i1; sSelS[t][1] = __expf(l[i1] - mx) / denom;
    }
  }
  __syncthreads();
  if (tid < RT_TOK) {
    lOff[tid][0] = (unsigned char)atomicAdd(&lCnt[eSelS[tid][0]], 1);
    lOff[tid][1] = (unsigned char)atomicAdd(&lCnt[eSelS[tid][1]], 1);
  }
  __syncthreads();
  if (tid < E_NUM) lBase[tid] = atomicAdd(&counts[tid * 32], lCnt[tid]);
  __syncthreads();
  if (tid < RT_TOK) {
    int b = blockIdx.x * RT_TOK + tid;
#pragma unroll
    for (int j = 0; j < 2; j++) {
      int e = eSelS[tid][j];
      int pos = lBase[e] + lOff[tid][j];
      if (pos < CAP) {
        int slot = e * CAP + pos;
        bucket[slot] = b;
        scoreB[slot] = sSelS[tid][j];
        slotOf[b * 2 + j] = slot;
      }
    }
  }
}

// ---------------- phase 2: grouped GEMM (interleaved v/g) + SwiGLU ----------------
// 256x256x64 tile, 8 waves (2M x 4N), 130 KB LDS double-buffer.
// ALL fragment loads are inline-asm ds_read_b128 with compile-time offset
// immediates so the COMPILER emits no LDS reads in the K-loop -> it cannot
// insert conservative s_waitcnt vmcnt(0) against outstanding global_load_lds
// (the failure mode that degenerated R1's counted-vmcnt schedule to drain-0).
// Rule #18: inline-asm lgkmcnt(0) must be followed by sched_barrier(0) or
// hipcc hoists the register-only MFMAs past the wait.
//
// Per-phase: {asm ds_read frags; issue 2 gl2lds(next tile); s_barrier;
//             lgkmcnt(0); sched_barrier(0); setprio(1); 16 MFMA; setprio(0);
//             vmcnt(4); s_barrier}
// FIFO invariant at tile top: 4 outstanding DMAs (A-hi,B-hi of current tile);
// vmcnt(4) at P0/P1/P3 retires exactly the half-tile the next phase reads;
// 2-4 half-tiles stay in flight across every barrier (never drained to 0).
// Address math: row&7 == lr&7 (all row bases are multiples of 8), so the XOR
// swizzle term is lane-constant and every fragment address is
//   base(lane,s) + [cb*32768 + hi*16384 + frag*2048]  (compile-time immediate).
// K-loop unrolled x2 so cb is compile-time; last two tiles peeled (tile 14
// stages tile 15; tile 15 drains with vmcnt(2)/vmcnt(0), no barriers).

#define DSR(dst, areg, IMM)                                                   \
  asm volatile("ds_read_b128 %0, %1 offset:%c2"                               \
               : "=v"(dst) : "v"(areg), "i"(IMM))

#define RD_A(CB, HI) do {                                                     \
    DSR(af[0][0], aA0, (CB)*32768 + (HI)*16384 + 0);                          \
    DSR(af[0][1], aA1, (CB)*32768 + (HI)*16384 + 0);                          \
    DSR(af[1][0], aA0, (CB)*32768 + (HI)*16384 + 2048);                       \
    DSR(af[1][1], aA1, (CB)*32768 + (HI)*16384 + 2048);                       \
    DSR(af[2][0], aA0, (CB)*32768 + (HI)*16384 + 4096);                       \
    DSR(af[2][1], aA1, (CB)*32768 + (HI)*16384 + 4096);                       \
    DSR(af[3][0], aA0, (CB)*32768 + (HI)*16384 + 6144);                       \
    DSR(af[3][1], aA1, (CB)*32768 + (HI)*16384 + 6144);                       \
  } while (0)

#define RD_B(CB, HI) do {                                                     \
    DSR(bf[0][0], bB0, (CB)*32768 + (HI)*16384 + 0);                          \
    DSR(bf[0][1], bB1, (CB)*32768 + (HI)*16384 + 0);                          \
    DSR(bf[1][0], bB0, (CB)*32768 + (HI)*16384 + 2048);                       \
    DSR(bf[1][1], bB1, (CB)*32768 + (HI)*16384 + 2048);                       \
  } while (0)

#define MFMA_Q(MO, NO)                                                        \
  {                                                                           \
    _Pragma("unroll") for (int m = 0; m < 4; m++) {                           \
      _Pragma("unroll") for (int n = 0; n < 2; n++) {                         \
        _Pragma("unroll") for (int s = 0; s < 2; s++) {                       \
          acc[(MO) + m][(NO) + n] = __builtin_amdgcn_mfma_f32_16x16x32_f16(   \
              af[m][s], bf[n][s], acc[(MO) + m][(NO) + n], 0, 0, 0);          \
        }                                                                     \
      }                                                                       \
    }                                                                         \
  }

#define PH_BAR() __builtin_amdgcn_s_barrier()
#define LGKM0() do {                                                          \
    asm volatile("s_waitcnt lgkmcnt(0)" ::: "memory");                        \
    __builtin_amdgcn_sched_barrier(0);                                        \
  } while (0)
#define VMW(N) asm volatile("s_waitcnt vmcnt(" #N ")" ::: "memory")
#define PRIO1() __builtin_amdgcn_s_setprio(1)
#define PRIO0() __builtin_amdgcn_s_setprio(0)

// one full K-tile with staging of the next tile (all main tiles)
#define TILE_STG(CB) do {                                                     \
    /* P0: (m-lo, n-lo); stage A-lo(next) */                                  \
    RD_A(CB, 0); RD_B(CB, 0);                                                 \
    gl2lds16(pA[0], &As[(CB) ^ 1][0 * 4096 + dst0]);                          \
    gl2lds16(pA[1], &As[(CB) ^ 1][1 * 4096 + dst0]);                          \
    PH_BAR(); LGKM0();                                                        \
    PRIO1(); MFMA_Q(0, 0); PRIO0();                                           \
    VMW(4); PH_BAR();                                                         \
    /* P1: (m-hi, n-lo); stage B-lo(next) */                                  \
    RD_A(CB, 1);                                                              \
    gl2lds16(pB[0], &Bs[(CB) ^ 1][0 * 4096 + dst0]);                          \
    gl2lds16(pB[1], &Bs[(CB) ^ 1][1 * 4096 + dst0]);                          \
    PH_BAR(); LGKM0();                                                        \
    PRIO1(); MFMA_Q(4, 0); PRIO0();                                           \
    VMW(4); PH_BAR();                                                         \
    /* P2: (m-hi, n-hi); stage A-hi(next) */                                  \
    RD_B(CB, 1);                                                              \
    gl2lds16(pA[2], &As[(CB) ^ 1][2 * 4096 + dst0]);                          \
    gl2lds16(pA[3], &As[(CB) ^ 1][3 * 4096 + dst0]);                          \
    PH_BAR(); LGKM0();                                                        \
    PRIO1(); MFMA_Q(4, 2); PRIO0();                                           \
    PH_BAR();                                                                 \
    /* P3: (m-lo, n-hi); stage B-hi(next) */                                  \
    RD_A(CB, 0);                                                              \
    gl2lds16(pB[2], &Bs[(CB) ^ 1][2 * 4096 + dst0]);                          \
    gl2lds16(pB[3], &Bs[(CB) ^ 1][3 * 4096 + dst0]);                          \
    PH_BAR(); LGKM0();                                                        \
    PRIO1(); MFMA_Q(0, 2); PRIO0();                                           \
    VMW(4); PH_BAR();                                                         \
    _Pragma("unroll") for (int i = 0; i < 4; i++) { pA[i] += BK; pB[i] += BK; } \
  } while (0)

template <bool USE_PARTIAL>
__global__ __launch_bounds__(512, 2) void moe_gemm_kernel(
    const unsigned short* __restrict__ xh, const unsigned short* __restrict__ Wc,
    const int* __restrict__ counts, const int* __restrict__ bucket,
    const float* __restrict__ scoreB, _Float16* __restrict__ partial,
    float* __restrict__ out, int B) {
  int e = blockIdx.z;
  int cnt = counts[e * 32];
  int m0 = blockIdx.x * BM;
  if (m0 >= cnt) return;
  int n0 = blockIdx.y * BN;

  __shared__ unsigned short As[2][BM * BK];  // 64 KB
  __shared__ unsigned short Bs[2][BN * BK];  // 64 KB
  __shared__ int tokS[BM];
  __shared__ float scS[BM];

  int tid = threadIdx.x;
  if (tid < BM) {
    int gr = m0 + tid;
    bool vld = gr < cnt;
    tokS[tid] = vld ? bucket[e * CAP + gr] : 0;
    scS[tid] = vld ? scoreB[e * CAP + gr] : 0.0f;  // padded rows contribute 0
  }
  __syncthreads();

  int wid = tid >> 6, lane = tid & 63;
  int wm = wid & 1, wn = wid >> 1;  // 2 (M) x 4 (N)
  int quad = lane >> 4, lr = lane & 15;

  // staging source pointers: thread covers row i*64 + (tid>>3), chunk tid&7,
  // with inverse XOR swizzle folded into the global k-offset.
  int rA = tid >> 3;                      // 0..63
  int ksw = ((tid & 7) ^ (rA & 7)) * 8;   // halves
  const unsigned short* WcE = Wc + (size_t)e * (2 * H_DIM) * D_DIM;
  const unsigned short* pA[4];
  const unsigned short* pB[4];
#pragma unroll
  for (int i = 0; i < 4; i++) {
    pA[i] = xh + (size_t)tokS[i * 64 + rA] * D_DIM + ksw;
    pB[i] = WcE + (size_t)(n0 + i * 64 + rA) * D_DIM + ksw;
  }
  int dst0 = tid * 8;  // halves; half-tile i at +i*4096

  // fragment LDS base addresses (bytes). row&7 == lr&7 for every fragment row,
  // so the swizzle term is lane-constant: addr = base_s + compile-time imm.
  unsigned swz0 = (unsigned)(((0 * 4 + quad) ^ (lr & 7)) * 16);
  unsigned swz1 = (unsigned)(((1 * 4 + quad) ^ (lr & 7)) * 16);
  unsigned ldsA = ldsaddr(&As[0][0]);
  unsigned ldsB = ldsaddr(&Bs[0][0]);
  unsigned aA0 = ldsA + (unsigned)(wm * 8192 + lr * 128) + swz0;
  unsigned aA1 = ldsA + (unsigned)(wm * 8192 + lr * 128) + swz1;
  unsigned bB0 = ldsB + (unsigned)(wn * 4096 + lr * 128) + swz0;
  unsigned bB1 = ldsB + (unsigned)(wn * 4096 + lr * 128) + swz1;

  f4v acc[8][4];
#pragma unroll
  for (int m = 0; m < 8; m++)
#pragma unroll
    for (int n = 0; n < 4; n++) acc[m][n] = (f4v){0.f, 0.f, 0.f, 0.f};

  // prologue: stage tile 0 (FIFO order: A-lo, B-lo, A-hi, B-hi)
  gl2lds16(pA[0], &As[0][0 * 4096 + dst0]);
  gl2lds16(pA[1], &As[0][1 * 4096 + dst0]);
  gl2lds16(pB[0], &Bs[0][0 * 4096 + dst0]);
  gl2lds16(pB[1], &Bs[0][1 * 4096 + dst0]);
  gl2lds16(pA[2], &As[0][2 * 4096 + dst0]);
  gl2lds16(pA[3], &As[0][3 * 4096 + dst0]);
  gl2lds16(pB[2], &Bs[0][2 * 4096 + dst0]);
  gl2lds16(pB[3], &Bs[0][3 * 4096 + dst0]);
#pragma unroll
  for (int i = 0; i < 4; i++) { pA[i] += BK; pB[i] += BK; }
  VMW(4);  // A-lo, B-lo of tile 0 landed
  PH_BAR();

  h8v af[4][2], bf[2][2];

  // tiles 0..13 (cb compile-time via x2 unroll), staging tiles 1..14
  for (int it = 0; it < 7; ++it) {
    TILE_STG(0);
    TILE_STG(1);
  }
  // tile 14 (cb=0), stages tile 15 into buf 1
  TILE_STG(0);

  // tile 15 (cb=1), no staging: drain waits, no barriers needed (no LDS writes)
  {
    // entry: 4 outstanding [A-hi(15), B-hi(15)]
    RD_A(1, 0); RD_B(1, 0);
    LGKM0();
    PRIO1(); MFMA_Q(0, 0); PRIO0();
    VMW(2);  // A-hi(15) landed
    RD_A(1, 1);
    LGKM0();
    PRIO1(); MFMA_Q(4, 0); PRIO0();
    VMW(0);  // B-hi(15) landed
    RD_B(1, 1);
    LGKM0();
    PRIO1(); MFMA_Q(4, 2); PRIO0();
    RD_A(1, 0);
    LGKM0();
    PRIO1(); MFMA_Q(0, 2); PRIO0();
  }

  // epilogue: acc[m][2p]=v, acc[m][2p+1]=g at identical h (interleaved Wc).
  // C/D layout: col = lane&15, row = quad*4 + reg  [measured m89/m91]
  int hb = blockIdx.y * 128 + wn * 16 + lr;
#pragma unroll
  for (int m = 0; m < 8; m++) {
    int rb = ((m < 4) ? (wm * 64 + m * 16) : (128 + wm * 64 + (m - 4) * 16)) + quad * 4;
#pragma unroll
    for (int r = 0; r < 4; r++) {
      int rr = rb + r;
      float sc = scS[rr];
      if (USE_PARTIAL) {
        _Float16* pr = partial + (size_t)(e * CAP + m0 + rr) * H_DIM;
#pragma unroll
        for (int p = 0; p < 2; p++) {
          float v = acc[m][2 * p][r];
          float g = acc[m][2 * p + 1][r];
          pr[hb + p * 64] = (_Float16)(v * sc / (1.0f + __expf(-g)));
        }
      } else {
        int tok = tokS[rr];
#pragma unroll
        for (int p = 0; p < 2; p++) {
          float v = acc[m][2 * p][r];
          float g = acc[m][2 * p + 1][r];
          atomicAdd(&out[(size_t)tok * H_DIM + hb + p * 64],
                    v * sc / (1.0f + __expf(-g)));
        }
      }
    }
  }
}

// ---------------- phase 3: gather (out[b] = partial[s0] + partial[s1]) ----------
__global__ __launch_bounds__(256) void gather_kernel(
    const _Float16* __restrict__ partial, const int* __restrict__ slotOf,
    float* __restrict__ out) {
  int b = blockIdx.x * 2 + (threadIdx.x >> 7);  // 2 tokens/block
  int t = threadIdx.x & 127;                     // 8 halves per thread
  int s0 = slotOf[b * 2], s1 = slotOf[b * 2 + 1];
  if ((unsigned)s0 >= E_NUM * CAP) s0 = 0;  // poison guard (overflow ~impossible)
  if ((unsigned)s1 >= E_NUM * CAP) s1 = 0;
  h8v a = ((const h8v*)(partial + (size_t)s0 * H_DIM))[t];
  h8v c = ((const h8v*)(partial + (size_t)s1 * H_DIM))[t];
  float4 o0, o1;
  o0.x = (float)a[0] + (float)c[0];
  o0.y = (float)a[1] + (float)c[1];
  o0.z = (float)a[2] + (float)c[2];
  o0.w = (float)a[3] + (float)c[3];
  o1.x = (float)a[4] + (float)c[4];
  o1.y = (float)a[5] + (float)c[5];
  o1.z = (float)a[6] + (float)c[6];
  o1.w = (float)a[7] + (float)c[7];
  float4* op = (float4*)(out + (size_t)b * H_DIM);
  op[t * 2] = o0;
  op[t * 2 + 1] = o1;
}

extern "C" void kernel_launch(void* const* d_in, const int* in_sizes, int n_in,
                              void* d_out, int out_size, void* d_ws, size_t ws_size,
                              hipStream_t stream) {
  const float* x = (const float*)d_in[0];
  const float* Wv = (const float*)d_in[1];
  const float* Wg = (const float*)d_in[2];
  const float* gw = (const float*)d_in[3];
  const float* gb = (const float*)d_in[4];
  float* out = (float*)d_out;
  const int B = in_sizes[0] / D_DIM;  // 16384

  char* ws = (char*)d_ws;
  unsigned short* xh = (unsigned short*)ws;                       // 32 MB
  size_t off = (size_t)B * D_DIM * 2;
  unsigned short* Wc = (unsigned short*)(ws + off);               // 32 MB (interleaved v/g)
  off += (size_t)E_NUM * (2 * H_DIM) * D_DIM * 2;
  int* counts = (int*)(ws + off);                                 // 8 padded counters
  off += 4096;
  int* bucket = (int*)(ws + off);                                 // E*CAP ints
  off += (size_t)E_NUM * CAP * 4;
  float* scoreB = (float*)(ws + off);                             // E*CAP floats
  off += (size_t)E_NUM * CAP * 4;
  int* slotOf = (int*)(ws + off);                                 // B*2 ints
  off += (size_t)B * 2 * 4;
  _Float16* partial = (_Float16*)(ws + off);                      // E*CAP*H fp16 = 80 MB
  size_t need = off + (size_t)E_NUM * CAP * H_DIM * 2;
  bool use_partial = ws_size >= need;

  hipMemsetAsync(counts, 0, 4096, stream);
  if (!use_partial) hipMemsetAsync(d_out, 0, (size_t)out_size * 4, stream);

  router_kernel<<<B / RT_TOK, 256, 0, stream>>>(
      (const float4*)x, (const float4*)gw, gb, counts, bucket, scoreB, slotOf,
      (ushort4*)xh, B);
  transpose_w_kernel<<<dim3(H_DIM / 64, D_DIM / 64, 2 * E_NUM), 256, 0, stream>>>(
      Wv, Wg, Wc);
  if (use_partial) {
    moe_gemm_kernel<true><<<dim3(CAP / BM, (2 * H_DIM) / BN, E_NUM), 512, 0, stream>>>(
        xh, Wc, counts, bucket, scoreB, partial, out, B);
    gather_kernel<<<B / 2, 256, 0, stream>>>(partial, slotOf, out);
  } else {
    moe_gemm_kernel<false><<<dim3(CAP / BM, (2 * H_DIM) / BN, E_NUM), 512, 0, stream>>>(
        xh, Wc, counts, bucket, scoreB, partial, out, B);
  }
}

// Round 3
// 353.910 us; speedup vs baseline: 1.0519x; 1.0495x over previous
//
#include <hip/hip_runtime.h>

#define D_DIM 1024
#define H_DIM 1024
#define E_NUM 8
#define BM 256
#define BN 256        // in interleaved v/g column space (2*H per expert)
#define BK 64
#define NT (D_DIM / BK)
#define CAP 5120      // per-expert bucket capacity (mean 4096, sigma ~60; >17 sigma)
#define RT_TOK 32     // tokens per router block
#define RT_BLKS (16384 / RT_TOK)          // 512 router blocks
#define TW_BLKS (16 * 16 * 2 * E_NUM)     // 4096 transpose blocks

typedef __attribute__((ext_vector_type(8))) _Float16 h8v;
typedef __attribute__((ext_vector_type(4))) float f4v;

__device__ __forceinline__ unsigned short f2h(float f) {
  union { _Float16 h; unsigned short u; } c;
  c.h = (_Float16)f;  // v_cvt_f16_f32, RNE
  return c.u;
}

// async 16B global->LDS DMA; LDS dest = wave-uniform base + lane*16
__device__ __forceinline__ void gl2lds16(const void* g, void* l) {
  __builtin_amdgcn_global_load_lds(
      (const __attribute__((address_space(1))) unsigned int*)g,
      (__attribute__((address_space(3))) unsigned int*)l, 16, 0, 0);
}

// generic (flat) LDS pointer -> 32-bit LDS byte offset for raw ds_read asm
__device__ __forceinline__ unsigned ldsaddr(const void* p) {
  return (unsigned)(unsigned long long)(const __attribute__((address_space(3))) void*)p;
}

// ---------------- phase 0+1 merged: prep kernel ----------------
// blocks [0, RT_BLKS): router (fp32 exact top-2) + fused x->fp16 convert
// blocks [RT_BLKS, RT_BLKS+TW_BLKS): W [E][D][H] fp32 -> Wc [E][2H][D] fp16
//   interleaved; n = (h>>4)*32 + mat*16 + (h&15)  (mat 0=Wv, 1=Wg)
// Independent data; merged to overlap the two memory-bound passes.
__global__ __launch_bounds__(256) void prep_kernel(
    const float4* __restrict__ x4, const float4* __restrict__ gw4,
    const float* __restrict__ gb, int* __restrict__ counts,
    int* __restrict__ bucket, float* __restrict__ scoreB,
    int* __restrict__ slotOf, ushort4* __restrict__ xh4,
    const float* __restrict__ Wv, const float* __restrict__ Wg,
    unsigned short* __restrict__ Wc) {
  __shared__ float4 gwS[E_NUM * 256];  // 32 KB (router)
  __shared__ float tile[64][65];       // 16.6 KB (transpose)
  __shared__ short eSelS[RT_TOK][2];
  __shared__ float sSelS[RT_TOK][2];
  __shared__ int lCnt[E_NUM], lBase[E_NUM];
  __shared__ unsigned char lOff[RT_TOK][2];
  int tid = threadIdx.x;
  int bid = blockIdx.x;

  if (bid >= RT_BLKS) {
    // ---------------- transpose path ----------------
    int fb = bid - RT_BLKS;
    int hx = fb & 15, dy = (fb >> 4) & 15, z = fb >> 8;
    const float* W = (z & 1) ? Wg : Wv;
    int mat = z & 1;
    int e = z >> 1;
    int h0 = hx * 64, d0 = dy * 64;
    const float* Wp = W + (size_t)e * D_DIM * H_DIM;
    unsigned short* Wcp = Wc + (size_t)e * (2 * H_DIM) * D_DIM;
#pragma unroll
    for (int j = 0; j < 4; j++) {  // 1024 float4 loads, 4/thread
      int id = tid + 256 * j;
      int dd = id >> 4, hc = id & 15;
      float4 v = *(const float4*)(Wp + (size_t)(d0 + dd) * H_DIM + h0 + hc * 4);
      tile[dd][hc * 4 + 0] = v.x;
      tile[dd][hc * 4 + 1] = v.y;
      tile[dd][hc * 4 + 2] = v.z;
      tile[dd][hc * 4 + 3] = v.w;
    }
    __syncthreads();
#pragma unroll
    for (int j = 0; j < 2; j++) {  // 512 uint4 (8-half) stores, 2/thread
      int id = tid + 256 * j;
      int h_ = id >> 3, dc = id & 7;
      unsigned short tmp[8];
#pragma unroll
      for (int k = 0; k < 8; k++) tmp[k] = f2h(tile[dc * 8 + k][h_]);
      int hg = h0 + h_;
      int ng = ((hg >> 4) << 5) | (mat << 4) | (hg & 15);
      *(uint4*)(Wcp + (size_t)ng * D_DIM + d0 + dc * 8) = *(uint4*)tmp;
    }
    return;
  }

  // ---------------- router path ----------------
  for (int i = tid; i < E_NUM * 256; i += 256) gwS[i] = gw4[i];
  if (tid < E_NUM) lCnt[tid] = 0;
  __syncthreads();
  int wid = tid >> 6, lane = tid & 63;
  for (int rep = 0; rep < RT_TOK / 4; rep++) {
    int t = wid * (RT_TOK / 4) + rep;
    int b = bid * RT_TOK + t;
    float acc[E_NUM];
#pragma unroll
    for (int e = 0; e < E_NUM; e++) acc[e] = 0.0f;
#pragma unroll
    for (int i = 0; i < 4; i++) {
      float4 xv = x4[(size_t)b * 256 + i * 64 + lane];
      ushort4 o;
      o.x = f2h(xv.x); o.y = f2h(xv.y); o.z = f2h(xv.z); o.w = f2h(xv.w);
      xh4[(size_t)b * 256 + i * 64 + lane] = o;  // fused fp16 convert
#pragma unroll
      for (int e = 0; e < E_NUM; e++) {
        float4 w = gwS[e * 256 + i * 64 + lane];
        acc[e] += xv.x * w.x + xv.y * w.y + xv.z * w.z + xv.w * w.w;
      }
    }
#pragma unroll
    for (int e = 0; e < E_NUM; e++) {
#pragma unroll
      for (int off = 32; off > 0; off >>= 1) acc[e] += __shfl_down(acc[e], off);
    }
    if (lane == 0) {
      float l[E_NUM];
#pragma unroll
      for (int e = 0; e < E_NUM; e++) l[e] = acc[e] + gb[e];
      int i0 = 0;
#pragma unroll
      for (int e = 1; e < E_NUM; e++) if (l[e] > l[i0]) i0 = e;
      int i1 = (i0 == 0) ? 1 : 0;
#pragma unroll
      for (int e = 0; e < E_NUM; e++) if (e != i0 && l[e] > l[i1]) i1 = e;
      float mx = l[i0];
      float denom = 0.0f;
#pragma unroll
      for (int e = 0; e < E_NUM; e++) denom += __expf(l[e] - mx);
      eSelS[t][0] = (short)i0; sSelS[t][0] = 1.0f / denom;
      eSelS[t][1] = (short)i1; sSelS[t][1] = __expf(l[i1] - mx) / denom;
    }
  }
  __syncthreads();
  if (tid < RT_TOK) {
    lOff[tid][0] = (unsigned char)atomicAdd(&lCnt[eSelS[tid][0]], 1);
    lOff[tid][1] = (unsigned char)atomicAdd(&lCnt[eSelS[tid][1]], 1);
  }
  __syncthreads();
  if (tid < E_NUM) lBase[tid] = atomicAdd(&counts[tid * 32], lCnt[tid]);
  __syncthreads();
  if (tid < RT_TOK) {
    int b = bid * RT_TOK + tid;
#pragma unroll
    for (int j = 0; j < 2; j++) {
      int e = eSelS[tid][j];
      int pos = lBase[e] + lOff[tid][j];
      if (pos < CAP) {
        int slot = e * CAP + pos;
        bucket[slot] = b;
        scoreB[slot] = sSelS[tid][j];
        slotOf[b * 2 + j] = slot;
      }
    }
  }
}

// ---------------- phase 2: grouped GEMM (interleaved v/g) + SwiGLU ----------------
// 256x256x64 tile, 8 waves (2M x 4N), 130 KB LDS double-buffer.
// CONVOY-BREAKING schedule (R3): three schedules (R0/R1/R2) all measured
// ~35% MfmaUtil; phase time fit LDS(714cy)+MFMA(620cy) SERIAL exactly.
// Fixes: (1) two-stage counted lgkmcnt so the s=0 MFMA batch starts while
// s=1 reads are still in flight; (2) zigzag quadrant order (0,0)->(0,2)->
// (4,2)->(4,0) so the per-tile re-read is B (4 reads) not A (8): 28 reads
// vs 32; (3) ONE barrier per phase (none after P2): read-completion before
// barrier guaranteed by in-phase lgkmcnt(0); (4) counted vmcnt, DMA issue
// P0:Alo(+1) P1:Blo(+1) P2:Bhi(+1) P3:Ahi(+1), waits P0/P1/P3: vmcnt(4)
// (every retired DMA issued >=2 phases prior).
// Rule #18: every counted lgkm wait is followed by sched_barrier(0).

#define DSR(dst, areg, IMM)                                                   \
  asm volatile("ds_read_b128 %0, %1 offset:%c2"                               \
               : "=v"(dst) : "v"(areg), "i"(IMM))

#define OFFS(CB, HI) ((CB) * 32768 + (HI) * 16384)

// P0: 12 reads, first 6 enable s=0 (bf-lo pair + af-lo s=0 quads)
#define RD12_P0(CB) do {                                                      \
    DSR(bf[0][0], bB0, OFFS(CB, 0) + 0);                                      \
    DSR(bf[1][0], bB0, OFFS(CB, 0) + 2048);                                   \
    DSR(af[0][0], aA0, OFFS(CB, 0) + 0);                                      \
    DSR(af[1][0], aA0, OFFS(CB, 0) + 2048);                                   \
    DSR(af[2][0], aA0, OFFS(CB, 0) + 4096);                                   \
    DSR(af[3][0], aA0, OFFS(CB, 0) + 6144);                                   \
    DSR(bf[0][1], bB1, OFFS(CB, 0) + 0);                                      \
    DSR(bf[1][1], bB1, OFFS(CB, 0) + 2048);                                   \
    DSR(af[0][1], aA1, OFFS(CB, 0) + 0);                                      \
    DSR(af[1][1], aA1, OFFS(CB, 0) + 2048);                                   \
    DSR(af[2][1], aA1, OFFS(CB, 0) + 4096);                                   \
    DSR(af[3][1], aA1, OFFS(CB, 0) + 6144);                                   \
  } while (0)

// 8 A reads: s=0 quad first, then s=1
#define RD8_A(CB, HI) do {                                                    \
    DSR(af[0][0], aA0, OFFS(CB, HI) + 0);                                     \
    DSR(af[1][0], aA0, OFFS(CB, HI) + 2048);                                  \
    DSR(af[2][0], aA0, OFFS(CB, HI) + 4096);                                  \
    DSR(af[3][0], aA0, OFFS(CB, HI) + 6144);                                  \
    DSR(af[0][1], aA1, OFFS(CB, HI) + 0);                                     \
    DSR(af[1][1], aA1, OFFS(CB, HI) + 2048);                                  \
    DSR(af[2][1], aA1, OFFS(CB, HI) + 4096);                                  \
    DSR(af[3][1], aA1, OFFS(CB, HI) + 6144);                                  \
  } while (0)

// 4 B reads: s=0 pair first
#define RD4_B(CB, HI) do {                                                    \
    DSR(bf[0][0], bB0, OFFS(CB, HI) + 0);                                     \
    DSR(bf[1][0], bB0, OFFS(CB, HI) + 2048);                                  \
    DSR(bf[0][1], bB1, OFFS(CB, HI) + 0);                                     \
    DSR(bf[1][1], bB1, OFFS(CB, HI) + 2048);                                  \
  } while (0)

// 8 MFMAs of one (quadrant, s) slice
#define MFMA_S(MO, NO, S)                                                     \
  {                                                                           \
    _Pragma("unroll") for (int m = 0; m < 4; m++) {                           \
      _Pragma("unroll") for (int n = 0; n < 2; n++) {                         \
        acc[(MO) + m][(NO) + n] = __builtin_amdgcn_mfma_f32_16x16x32_f16(     \
            af[m][S], bf[n][S], acc[(MO) + m][(NO) + n], 0, 0, 0);            \
      }                                                                       \
    }                                                                         \
  }

#define PH_BAR() __builtin_amdgcn_s_barrier()
#define LGKM(N) do {                                                          \
    asm volatile("s_waitcnt lgkmcnt(" #N ")" ::: "memory");                   \
    __builtin_amdgcn_sched_barrier(0);                                        \
  } while (0)
#define VMW(N) asm volatile("s_waitcnt vmcnt(" #N ")" ::: "memory")
#define PRIO1() __builtin_amdgcn_s_setprio(1)
#define PRIO0() __builtin_amdgcn_s_setprio(0)

// one full K-tile, staging next tile (main tiles)
#define TILE_N(CB) do {                                                       \
    /* P0: (m-lo,n-lo); reads Alo+Blo; DMA Alo(next) */                       \
    RD12_P0(CB);                                                              \
    gl2lds16(pA[0], &As[(CB) ^ 1][0 * 4096 + dst0]);                          \
    gl2lds16(pA[1], &As[(CB) ^ 1][1 * 4096 + dst0]);                          \
    LGKM(6);  PRIO1(); MFMA_S(0, 0, 0); PRIO0();                              \
    LGKM(0);  PRIO1(); MFMA_S(0, 0, 1); PRIO0();                              \
    VMW(4); PH_BAR();                                                         \
    /* P1: (m-lo,n-hi); reads Bhi; DMA Blo(next) */                           \
    RD4_B(CB, 1);                                                             \
    gl2lds16(pB[0], &Bs[(CB) ^ 1][0 * 4096 + dst0]);                          \
    gl2lds16(pB[1], &Bs[(CB) ^ 1][1 * 4096 + dst0]);                          \
    LGKM(2);  PRIO1(); MFMA_S(0, 2, 0); PRIO0();                              \
    LGKM(0);  PRIO1(); MFMA_S(0, 2, 1); PRIO0();                              \
    VMW(4); PH_BAR();                                                         \
    /* P2: (m-hi,n-hi); reads Ahi; DMA Bhi(next); NO barrier */               \
    RD8_A(CB, 1);                                                             \
    gl2lds16(pB[2], &Bs[(CB) ^ 1][2 * 4096 + dst0]);                          \
    gl2lds16(pB[3], &Bs[(CB) ^ 1][3 * 4096 + dst0]);                          \
    LGKM(4);  PRIO1(); MFMA_S(4, 2, 0); PRIO0();                              \
    LGKM(0);  PRIO1(); MFMA_S(4, 2, 1); PRIO0();                              \
    /* P3: (m-hi,n-lo); reads Blo (re-read); DMA Ahi(next) */                 \
    RD4_B(CB, 0);                                                             \
    gl2lds16(pA[2], &As[(CB) ^ 1][2 * 4096 + dst0]);                          \
    gl2lds16(pA[3], &As[(CB) ^ 1][3 * 4096 + dst0]);                          \
    LGKM(2);  PRIO1(); MFMA_S(4, 0, 0); PRIO0();                              \
    LGKM(0);  PRIO1(); MFMA_S(4, 0, 1); PRIO0();                              \
    VMW(4); PH_BAR();                                                         \
    _Pragma("unroll") for (int i = 0; i < 4; i++) { pA[i] += BK; pB[i] += BK; } \
  } while (0)

template <bool USE_PARTIAL>
__global__ __launch_bounds__(512, 2) void moe_gemm_kernel(
    const unsigned short* __restrict__ xh, const unsigned short* __restrict__ Wc,
    const int* __restrict__ counts, const int* __restrict__ bucket,
    const float* __restrict__ scoreB, _Float16* __restrict__ partial,
    float* __restrict__ out, int B) {
  int e = blockIdx.z;
  int cnt = counts[e * 32];
  int m0 = blockIdx.x * BM;
  if (m0 >= cnt) return;
  int n0 = blockIdx.y * BN;

  __shared__ unsigned short As[2][BM * BK];  // 64 KB
  __shared__ unsigned short Bs[2][BN * BK];  // 64 KB
  __shared__ int tokS[BM];
  __shared__ float scS[BM];

  int tid = threadIdx.x;
  if (tid < BM) {
    int gr = m0 + tid;
    bool vld = gr < cnt;
    tokS[tid] = vld ? bucket[e * CAP + gr] : 0;
    scS[tid] = vld ? scoreB[e * CAP + gr] : 0.0f;  // padded rows contribute 0
  }
  __syncthreads();

  int wid = tid >> 6, lane = tid & 63;
  int wm = wid & 1, wn = wid >> 1;  // 2 (M) x 4 (N)
  int quad = lane >> 4, lr = lane & 15;

  // staging source pointers: thread covers row i*64 + (tid>>3), chunk tid&7,
  // with inverse XOR swizzle folded into the global k-offset.
  int rA = tid >> 3;                      // 0..63
  int ksw = ((tid & 7) ^ (rA & 7)) * 8;   // halves
  const unsigned short* WcE = Wc + (size_t)e * (2 * H_DIM) * D_DIM;
  const unsigned short* pA[4];
  const unsigned short* pB[4];
#pragma unroll
  for (int i = 0; i < 4; i++) {
    pA[i] = xh + (size_t)tokS[i * 64 + rA] * D_DIM + ksw;
    pB[i] = WcE + (size_t)(n0 + i * 64 + rA) * D_DIM + ksw;
  }
  int dst0 = tid * 8;  // halves; half-tile i at +i*4096

  // fragment LDS base addresses (bytes). row&7 == lr&7 for every fragment row,
  // so the swizzle term is lane-constant: addr = base + compile-time imm.
  unsigned swz0 = (unsigned)(((0 * 4 + quad) ^ (lr & 7)) * 16);
  unsigned swz1 = (unsigned)(((1 * 4 + quad) ^ (lr & 7)) * 16);
  unsigned ldsA = ldsaddr(&As[0][0]);
  unsigned ldsB = ldsaddr(&Bs[0][0]);
  unsigned aA0 = ldsA + (unsigned)(wm * 8192 + lr * 128) + swz0;
  unsigned aA1 = ldsA + (unsigned)(wm * 8192 + lr * 128) + swz1;
  unsigned bB0 = ldsB + (unsigned)(wn * 4096 + lr * 128) + swz0;
  unsigned bB1 = ldsB + (unsigned)(wn * 4096 + lr * 128) + swz1;

  f4v acc[8][4];
#pragma unroll
  for (int m = 0; m < 8; m++)
#pragma unroll
    for (int n = 0; n < 4; n++) acc[m][n] = (f4v){0.f, 0.f, 0.f, 0.f};

  // prologue: stage tile 0; FIFO order MUST be [Alo, Blo, Bhi, Ahi] to match
  // the steady-state per-tile issue order (P0..P3).
  gl2lds16(pA[0], &As[0][0 * 4096 + dst0]);
  gl2lds16(pA[1], &As[0][1 * 4096 + dst0]);
  gl2lds16(pB[0], &Bs[0][0 * 4096 + dst0]);
  gl2lds16(pB[1], &Bs[0][1 * 4096 + dst0]);
  gl2lds16(pB[2], &Bs[0][2 * 4096 + dst0]);
  gl2lds16(pB[3], &Bs[0][3 * 4096 + dst0]);
  gl2lds16(pA[2], &As[0][2 * 4096 + dst0]);
  gl2lds16(pA[3], &As[0][3 * 4096 + dst0]);
#pragma unroll
  for (int i = 0; i < 4; i++) { pA[i] += BK; pB[i] += BK; }
  VMW(4);  // A-lo, B-lo of tile 0 landed
  PH_BAR();

  h8v af[4][2], bf[2][2];

  // main tiles 0..14 (cb compile-time via x2 unroll), staging tiles 1..15
  for (int it = 0; it < 7; ++it) {
    TILE_N(0);
    TILE_N(1);
  }
  TILE_N(0);  // tile 14 (cb=0), stages tile 15 into buf 1

  // tail: tile 15 (cb=1), no staging. Entry outstanding: [Bhi(15), Ahi(15)]=4
  {
    RD12_P0(1);
    LGKM(6);  PRIO1(); MFMA_S(0, 0, 0); PRIO0();
    LGKM(0);  PRIO1(); MFMA_S(0, 0, 1); PRIO0();
    VMW(2); PH_BAR();  // Bhi(15) landed
    RD4_B(1, 1);
    LGKM(2);  PRIO1(); MFMA_S(0, 2, 0); PRIO0();
    LGKM(0);  PRIO1(); MFMA_S(0, 2, 1); PRIO0();
    VMW(0); PH_BAR();  // Ahi(15) landed
    RD8_A(1, 1);
    LGKM(4);  PRIO1(); MFMA_S(4, 2, 0); PRIO0();
    LGKM(0);  PRIO1(); MFMA_S(4, 2, 1); PRIO0();
    RD4_B(1, 0);
    LGKM(2);  PRIO1(); MFMA_S(4, 0, 0); PRIO0();
    LGKM(0);  PRIO1(); MFMA_S(4, 0, 1); PRIO0();
  }

  // epilogue: acc[m][2p]=v, acc[m][2p+1]=g at identical h (interleaved Wc).
  // C/D layout: col = lane&15, row = quad*4 + reg  [measured m89/m91]
  int hb = blockIdx.y * 128 + wn * 16 + lr;
#pragma unroll
  for (int m = 0; m < 8; m++) {
    int rb = ((m < 4) ? (wm * 64 + m * 16) : (128 + wm * 64 + (m - 4) * 16)) + quad * 4;
#pragma unroll
    for (int r = 0; r < 4; r++) {
      int rr = rb + r;
      float sc = scS[rr];
      if (USE_PARTIAL) {
        _Float16* pr = partial + (size_t)(e * CAP + m0 + rr) * H_DIM;
#pragma unroll
        for (int p = 0; p < 2; p++) {
          float v = acc[m][2 * p][r];
          float g = acc[m][2 * p + 1][r];
          pr[hb + p * 64] = (_Float16)(v * sc / (1.0f + __expf(-g)));
        }
      } else {
        int tok = tokS[rr];
#pragma unroll
        for (int p = 0; p < 2; p++) {
          float v = acc[m][2 * p][r];
          float g = acc[m][2 * p + 1][r];
          atomicAdd(&out[(size_t)tok * H_DIM + hb + p * 64],
                    v * sc / (1.0f + __expf(-g)));
        }
      }
    }
  }
}

// ---------------- phase 3: gather (out[b] = partial[s0] + partial[s1]) ----------
__global__ __launch_bounds__(256) void gather_kernel(
    const _Float16* __restrict__ partial, const int* __restrict__ slotOf,
    float* __restrict__ out) {
  int b = blockIdx.x * 2 + (threadIdx.x >> 7);  // 2 tokens/block
  int t = threadIdx.x & 127;                     // 8 halves per thread
  int s0 = slotOf[b * 2], s1 = slotOf[b * 2 + 1];
  if ((unsigned)s0 >= E_NUM * CAP) s0 = 0;  // poison guard (overflow ~impossible)
  if ((unsigned)s1 >= E_NUM * CAP) s1 = 0;
  h8v a = ((const h8v*)(partial + (size_t)s0 * H_DIM))[t];
  h8v c = ((const h8v*)(partial + (size_t)s1 * H_DIM))[t];
  float4 o0, o1;
  o0.x = (float)a[0] + (float)c[0];
  o0.y = (float)a[1] + (float)c[1];
  o0.z = (float)a[2] + (float)c[2];
  o0.w = (float)a[3] + (float)c[3];
  o1.x = (float)a[4] + (float)c[4];
  o1.y = (float)a[5] + (float)c[5];
  o1.z = (float)a[6] + (float)c[6];
  o1.w = (float)a[7] + (float)c[7];
  float4* op = (float4*)(out + (size_t)b * H_DIM);
  op[t * 2] = o0;
  op[t * 2 + 1] = o1;
}

extern "C" void kernel_launch(void* const* d_in, const int* in_sizes, int n_in,
                              void* d_out, int out_size, void* d_ws, size_t ws_size,
                              hipStream_t stream) {
  const float* x = (const float*)d_in[0];
  const float* Wv = (const float*)d_in[1];
  const float* Wg = (const float*)d_in[2];
  const float* gw = (const float*)d_in[3];
  const float* gb = (const float*)d_in[4];
  float* out = (float*)d_out;
  const int B = in_sizes[0] / D_DIM;  // 16384

  char* ws = (char*)d_ws;
  unsigned short* xh = (unsigned short*)ws;                       // 32 MB
  size_t off = (size_t)B * D_DIM * 2;
  unsigned short* Wc = (unsigned short*)(ws + off);               // 32 MB (interleaved v/g)
  off += (size_t)E_NUM * (2 * H_DIM) * D_DIM * 2;
  int* counts = (int*)(ws + off);                                 // 8 padded counters
  off += 4096;
  int* bucket = (int*)(ws + off);                                 // E*CAP ints
  off += (size_t)E_NUM * CAP * 4;
  float* scoreB = (float*)(ws + off);                             // E*CAP floats
  off += (size_t)E_NUM * CAP * 4;
  int* slotOf = (int*)(ws + off);                                 // B*2 ints
  off += (size_t)B * 2 * 4;
  _Float16* partial = (_Float16*)(ws + off);                      // E*CAP*H fp16 = 80 MB
  size_t need = off + (size_t)E_NUM * CAP * H_DIM * 2;
  bool use_partial = ws_size >= need;

  hipMemsetAsync(counts, 0, 4096, stream);
  if (!use_partial) hipMemsetAsync(d_out, 0, (size_t)out_size * 4, stream);

  prep_kernel<<<RT_BLKS + TW_BLKS, 256, 0, stream>>>(
      (const float4*)x, (const float4*)gw, gb, counts, bucket, scoreB, slotOf,
      (ushort4*)xh, Wv, Wg, Wc);
  if (use_partial) {
    moe_gemm_kernel<true><<<dim3(CAP / BM, (2 * H_DIM) / BN, E_NUM), 512, 0, stream>>>(
        xh, Wc, counts, bucket, scoreB, partial, out, B);
    gather_kernel<<<B / 2, 256, 0, stream>>>(partial, slotOf, out);
  } else {
    moe_gemm_kernel<false><<<dim3(CAP / BM, (2 * H_DIM) / BN, E_NUM), 512, 0, stream>>>(
        xh, Wc, counts, bucket, scoreB, partial, out, B);
  }
}